// Round 12
// baseline (90.785 us; speedup 1.0000x reference)
//
#include <hip/hip_runtime.h>

#define NQ 10
#define NL 5

typedef float v2f __attribute__((ext_vector_type(2)));

__device__ __forceinline__ v2f sp(float s) { v2f r = { s, s }; return r; }

// ---- forced packed fp32 (VOP3P). CK-style inline asm; 1 inst per 2 lanes-of-2. ----
__device__ __forceinline__ v2f pk_mul(v2f a, v2f b) {
    v2f d; asm("v_pk_mul_f32 %0, %1, %2" : "=v"(d) : "v"(a), "v"(b)); return d;
}
__device__ __forceinline__ v2f pk_fma(v2f a, v2f b, v2f c) {
    v2f d; asm("v_pk_fma_f32 %0, %1, %2, %3" : "=v"(d) : "v"(a), "v"(b), "v"(c)); return d;
}

// ---- cross-lane xor exchange (direct-partner masks), all VALU ----
template <int M>
__device__ __forceinline__ float lane_xor_direct(float v) {
    unsigned u = __float_as_uint(v);
    if constexpr (M == 1) {        // quad_perm [1,0,3,2]
        return __uint_as_float((unsigned)__builtin_amdgcn_update_dpp(0, (int)u, 0xB1, 0xF, 0xF, true));
    } else if constexpr (M == 2) { // quad_perm [2,3,0,1]
        return __uint_as_float((unsigned)__builtin_amdgcn_update_dpp(0, (int)u, 0x4E, 0xF, 0xF, true));
    } else if constexpr (M == 4) {
        // lanes i&4==0 need src[i+4] -> ROW_SHL:4; lanes i&4==4 need src[i-4] -> ROW_SHR:4
        int t = __builtin_amdgcn_update_dpp(0, (int)u, 0x104, 0xF, 0x5, false);
        t     = __builtin_amdgcn_update_dpp(t, (int)u, 0x114, 0xF, 0xA, false);
        return __uint_as_float((unsigned)t);
    } else {                       // M == 8: row_ror:8 == xor8 within 16
        return __uint_as_float((unsigned)__builtin_amdgcn_update_dpp(0, (int)u, 0x128, 0xF, 0xF, true));
    }
}

template <int M>
__device__ __forceinline__ void lane_swap_pair(float v, float& r0, float& r1) {
    unsigned u = __float_as_uint(v);
    if constexpr (M == 16) {
        auto r = __builtin_amdgcn_permlane16_swap(u, u, false, false);
        r0 = __uint_as_float(r[0]); r1 = __uint_as_float(r[1]);
    } else {
        auto r = __builtin_amdgcn_permlane32_swap(u, u, false, false);
        r0 = __uint_as_float(r[0]); r1 = __uint_as_float(r[1]);
    }
}

template <int M>
__device__ __forceinline__ float lane_xor(float v, int lane) {
    if constexpr (M < 16) {
        return lane_xor_direct<M>(v);
    } else {
        float r0, r1;
        lane_swap_pair<M>(v, r0, r1);
        return (lane & M) ? r0 : r1;
    }
}

// U = Rz(tz) @ Ry(ty) @ Rx(tx)  (SU(2): u11 = conj(u00), u10 = -conj(u01))
__device__ __forceinline__ void make_u(float tx, float ty, float tz,
                                       float& u00r, float& u00i, float& u01r, float& u01i) {
    float cx, sx, cy, sy, cz, sz;
    __sincosf(0.5f * tx, &sx, &cx);
    __sincosf(0.5f * ty, &sy, &cy);
    __sincosf(0.5f * tz, &sz, &cz);
    u00r =  cz * cy * cx + sz * sy * sx;
    u00i =  cz * sy * sx - sz * cy * cx;
    u01r = -cz * sy * cx - sz * cy * sx;
    u01i =  sz * sy * cx - cz * cy * sx;
}

// Setup: 60 gates x 8 floats (top rows of V0 and V1; W = c*V0 + s*V1 is SU(2)).
__global__ void pqc_setup(const float* __restrict__ theta, float* __restrict__ gm) {
    int g = threadIdx.x;
    if (g >= (NL + 1) * NQ) return;
    const float* th = theta + g * 3;
    float u00r, u00i, u01r, u01i;
    make_u(th[0], th[1], th[2], u00r, u00i, u01r, u01i);
    float* o = gm + g * 8;
    o[0] = u00r;  o[1] = u00i;  o[2] = u01r;  o[3] = u01i;
    o[4] = u01i;  o[5] = -u01r; o[6] = u00i;  o[7] = -u00r;
}

// State: amplitude k = lane*16 + r, r = 2*j + h.  fr[j]/fi[j] hold re/im of (r=2j, r=2j+1).
// Gate = [[a, b], [-conj(b), conj(a)]] given by (ar,ai,br,bi). All FMA forced to v_pk_*.
template <int P>
__device__ __forceinline__ void apply_p(v2f fr[8], v2f fi[8],
                                        float ar, float ai, float br, float bi, int lane) {
    if constexpr (P == 0) {
        v2f c0r = { ar, ar },  c0i = { ai, -ai }, nc0i = { -ai, ai };
        v2f c1r = { br, -br }, c1i = { bi, bi },  nc1i = { -bi, -bi };
#pragma unroll
        for (int j = 0; j < 8; ++j) {
            v2f av = fr[j], iv = fi[j];
            v2f srp = av.yx, sip = iv.yx;
            fr[j] = pk_fma(nc1i, sip, pk_fma(c1r, srp, pk_fma(nc0i, iv, pk_mul(c0r, av))));
            fi[j] = pk_fma(c1i,  srp, pk_fma(c1r, sip, pk_fma(c0i,  av, pk_mul(c0r, iv))));
        }
    } else if constexpr (P < 4) {
        constexpr int LJ = 1 << (P - 1);
        v2f arv = sp(ar), aiv = sp(ai), naiv = sp(-ai);
        v2f brv = sp(br), nbrv = sp(-br), biv = sp(bi), nbiv = sp(-bi);
#pragma unroll
        for (int base = 0; base < 8; ++base) {
            if (base & LJ) continue;
            v2f a0r = fr[base], a0i = fi[base];
            v2f a1r = fr[base | LJ], a1i = fi[base | LJ];
            fr[base]      = pk_fma(nbiv, a1i, pk_fma(brv, a1r, pk_fma(naiv, a0i, pk_mul(arv,  a0r))));
            fi[base]      = pk_fma(biv,  a1r, pk_fma(brv, a1i, pk_fma(aiv,  a0r, pk_mul(arv,  a0i))));
            fr[base | LJ] = pk_fma(aiv,  a1i, pk_fma(arv, a1r, pk_fma(nbiv, a0i, pk_mul(nbrv, a0r))));
            fi[base | LJ] = pk_fma(naiv, a1r, pk_fma(arv, a1i, pk_fma(biv,  a0r, pk_mul(nbrv, a0i))));
        }
    } else if constexpr (P < 8) {
        constexpr int M = 1 << (P - 4);
        const int bit = (lane >> (P - 4)) & 1;
        v2f pr = sp(ar), pi = sp(bit ? -ai : ai), npi = sp(bit ? ai : -ai);
        v2f qr = sp(bit ? -br : br), qi = sp(bi), nqi = sp(-bi);
#pragma unroll
        for (int j = 0; j < 8; ++j) {
            v2f ofr, ofi;
            ofr.x = lane_xor_direct<M>(fr[j].x);
            ofr.y = lane_xor_direct<M>(fr[j].y);
            ofi.x = lane_xor_direct<M>(fi[j].x);
            ofi.y = lane_xor_direct<M>(fi[j].y);
            v2f nr = pk_fma(nqi, ofi, pk_fma(qr, ofr, pk_fma(npi, fi[j], pk_mul(pr, fr[j]))));
            v2f ni = pk_fma(qi,  ofr, pk_fma(qr, ofi, pk_fma(pi,  fr[j], pk_mul(pr, fi[j]))));
            fr[j] = nr;
            fi[j] = ni;
        }
    } else {
        // permlane swap gives both halves: result = cA*r0 + cB*r1, no per-value selects.
        constexpr int M = 1 << (P - 4);
        const bool hi = (lane & M) != 0;
        v2f cAr = sp(hi ? -br : ar), cAi = sp(hi ? bi : ai), ncAi = sp(hi ? -bi : -ai);
        v2f cBr = sp(hi ? ar : br),  cBi = sp(hi ? -ai : bi), ncBi = sp(hi ? ai : -bi);
#pragma unroll
        for (int j = 0; j < 8; ++j) {
            float a0x, a1x, a0y, a1y, b0x, b1x, b0y, b1y;
            lane_swap_pair<M>(fr[j].x, a0x, a1x);
            lane_swap_pair<M>(fr[j].y, a0y, a1y);
            lane_swap_pair<M>(fi[j].x, b0x, b1x);
            lane_swap_pair<M>(fi[j].y, b0y, b1y);
            v2f A0r = { a0x, a0y }, A1r = { a1x, a1y };
            v2f A0i = { b0x, b0y }, A1i = { b1x, b1y };
            fr[j] = pk_fma(ncBi, A1i, pk_fma(cBr, A1r, pk_fma(ncAi, A0i, pk_mul(cAr, A0r))));
            fi[j] = pk_fma(cBi,  A1r, pk_fma(cBr, A1i, pk_fma(cAi,  A0r, pk_mul(cAr, A0i))));
        }
    }
}

// Fused gate: top row W = c*(g0..g3) + s*(g4..g7), 8 scalar FMAs.
#define GATE(qq, PP)                                                               \
    {                                                                              \
        const float* g = gl + (qq) * 8;                                            \
        float c = cc[qq], s = ss[qq];                                              \
        apply_p<PP>(fr, fi, c * g[0] + s * g[4], c * g[1] + s * g[5],              \
                            c * g[2] + s * g[6], c * g[3] + s * g[7], lane);       \
    }

// Layer-0 gate: W = V0 read directly (no sincos, no build).
#define GATE0(qq, PP)                                                              \
    {                                                                              \
        const float* g = gm + (qq) * 8;                                            \
        apply_p<PP>(fr, fi, g[0], g[1], g[2], g[3], lane);                         \
    }

__global__ void __launch_bounds__(64, 2) pqc_kernel(const float* __restrict__ x,
                                                    const float* __restrict__ lam,
                                                    const float* __restrict__ w,
                                                    const float* __restrict__ gm,
                                                    float* __restrict__ out, int B) {
    const int lane = threadIdx.x;
    const int b = blockIdx.x;

    v2f fr[8], fi[8];
#pragma unroll
    for (int j = 0; j < 8; ++j) { fr[j] = sp(0.f); fi[j] = sp(0.f); }
    if (lane == 0) fr[0].x = 1.f;

    // CZ-ring sign vectors and Z^n parity mask for this lane's 16 amplitudes.
    v2f sv[8];
    unsigned zmask = 0;
#pragma unroll
    for (int j = 0; j < 8; ++j) {
#pragma unroll
        for (int h = 0; h < 2; ++h) {
            int k = (lane << 4) | (2 * j + h);
            int par = (__popc(k & (k >> 1)) + ((k & (k >> 9)) & 1)) & 1;
            float s = __uint_as_float(0x3f800000u | ((unsigned)par << 31));
            if (h == 0) sv[j].x = s; else sv[j].y = s;
            zmask |= (unsigned)(__popc(k) & 1) << (2 * j + h);
        }
    }

    float xr[NQ];
#pragma unroll
    for (int q = 0; q < NQ; ++q) xr[q] = x[b * NQ + q];

    // Layer 0 (peeled): variational gates straight from V0, then CZ ring.
    GATE0(0, 9) GATE0(1, 8) GATE0(2, 7) GATE0(3, 6) GATE0(4, 5)
    GATE0(5, 4) GATE0(6, 3) GATE0(7, 2) GATE0(8, 1) GATE0(9, 0)
#pragma unroll
    for (int j = 0; j < 8; ++j) { fr[j] = pk_mul(fr[j], sv[j]); fi[j] = pk_mul(fi[j], sv[j]); }

    // Layers 1..NL: fused W = U_theta(l)*RX(x*lam(l-1)); CZ after each EXCEPT the last
    // (diag(+-1) before |amp|^2 is a no-op on the output).
#pragma clang loop unroll(disable)
    for (int l = 1; l <= NL; ++l) {
        const float* gl = gm + l * NQ * 8;
        const float* lm = lam + (l - 1) * NQ;
        float cc[NQ], ss[NQ];
#pragma unroll
        for (int q = 0; q < NQ; ++q)
            __sincosf(0.5f * xr[q] * lm[q], &ss[q], &cc[q]);
        GATE(0, 9) GATE(1, 8) GATE(2, 7) GATE(3, 6) GATE(4, 5)
        GATE(5, 4) GATE(6, 3) GATE(7, 2) GATE(8, 1) GATE(9, 0)
        if (l < NL) {
#pragma unroll
            for (int j = 0; j < 8; ++j) { fr[j] = pk_mul(fr[j], sv[j]); fi[j] = pk_mul(fi[j], sv[j]); }
        }
    }

    // <Z^n> = sum |amp|^2 * (-1)^popcount(k)
    v2f acc = sp(0.f);
#pragma unroll
    for (int j = 0; j < 8; ++j) {
        v2f zs;
        zs.x = __uint_as_float(0x3f800000u | (((zmask >> (2 * j)) & 1u) << 31));
        zs.y = __uint_as_float(0x3f800000u | (((zmask >> (2 * j + 1)) & 1u) << 31));
        v2f p = pk_fma(fi[j], fi[j], pk_mul(fr[j], fr[j]));
        acc = pk_fma(zs, p, acc);
    }
    float ez = acc.x + acc.y;
    ez += lane_xor<1>(ez, lane);
    ez += lane_xor<2>(ez, lane);
    ez += lane_xor<4>(ez, lane);
    ez += lane_xor<8>(ez, lane);
    ez += lane_xor<16>(ez, lane);
    ez += lane_xor<32>(ez, lane);

    if (lane == 0) {
        float l0 = ez * w[0], l1 = ez * w[1];   // BETA = 1
        float m = fmaxf(l0, l1);
        float e0 = __expf(l0 - m), e1 = __expf(l1 - m);
        float inv = 1.f / (e0 + e1);
        out[2 * b + 0] = e0 * inv;
        out[2 * b + 1] = e1 * inv;
    }
}

extern "C" void kernel_launch(void* const* d_in, const int* in_sizes, int n_in,
                              void* d_out, int out_size, void* d_ws, size_t ws_size,
                              hipStream_t stream) {
    const float* x     = (const float*)d_in[0];
    const float* theta = (const float*)d_in[1];
    const float* lam   = (const float*)d_in[2];
    const float* w     = (const float*)d_in[3];
    float* out = (float*)d_out;
    float* gm  = (float*)d_ws;                 // 60 gates * 8 floats = 1920 B

    const int B = in_sizes[0] / NQ;            // 2048
    hipLaunchKernelGGL(pqc_setup, dim3(1), dim3(64), 0, stream, theta, gm);
    hipLaunchKernelGGL(pqc_kernel, dim3(B), dim3(64), 0, stream,
                       x, lam, w, gm, out, B);
}